// Round 13
// baseline (10336.540 us; speedup 1.0000x reference)
//
#include <hip/hip_runtime.h>
#include <hip/hip_fp16.h>

typedef unsigned short u16;
typedef unsigned int u32;
typedef signed char i8;

#define E 2048
#define T_STEPS 512

// ---------------- helpers ----------------
// dequant 8 int4 (offset-8 nibbles) from one u32 against 8 h-values
__device__ __forceinline__ float dot8i4(u32 v, float4 a, float4 b, float acc) {
    acc = fmaf((float)((int)(v & 15u) - 8), a.x, acc);
    acc = fmaf((float)((int)((v >> 4) & 15u) - 8), a.y, acc);
    acc = fmaf((float)((int)((v >> 8) & 15u) - 8), a.z, acc);
    acc = fmaf((float)((int)((v >> 12) & 15u) - 8), a.w, acc);
    acc = fmaf((float)((int)((v >> 16) & 15u) - 8), b.x, acc);
    acc = fmaf((float)((int)((v >> 20) & 15u) - 8), b.y, acc);
    acc = fmaf((float)((int)((v >> 24) & 15u) - 8), b.z, acc);
    acc = fmaf((float)((int)(v >> 28) - 8), b.w, acc);
    return acc;
}
__device__ __forceinline__ float wred(float t) {
#pragma unroll
    for (int off = 32; off > 0; off >>= 1) t += __shfl_xor(t, off);
    return t;
}
__device__ __forceinline__ float sigm(float v) { return 1.f / (1.f + expf(-v)); }

// ---------------- prep kernels ----------------

// W_comb[r][c] = sum_k W_ih0[r][k] * W_out[k][c]  (fp32; 8192 x 2048)
__global__ __launch_bounds__(256) void k_wcomb(const float* __restrict__ wih0,
                                               const float* __restrict__ wout,
                                               float* __restrict__ wc) {
    __shared__ float a[8 * 128];
    int r0 = blockIdx.y * 8;
    int c = blockIdx.x * 256 + threadIdx.x;
    for (int i = threadIdx.x; i < 8 * 128; i += 256) a[i] = wih0[r0 * 128 + i];
    __syncthreads();
    float acc[8] = {0.f, 0.f, 0.f, 0.f, 0.f, 0.f, 0.f, 0.f};
    for (int k = 0; k < 128; ++k) {
        float b = wout[k * E + c];
#pragma unroll
        for (int j = 0; j < 8; ++j) acc[j] = fmaf(a[j * 128 + k], b, acc[j]);
    }
#pragma unroll
    for (int j = 0; j < 8; ++j) wc[(size_t)(r0 + j) * E + c] = acc[j];
}

// per-row int4 quantization into BLOCK-PACKED layout.
// input row r (of a 4E x E matrix): q = r>>11, e = r&2047
// packed row p = (e>>1)*16 + m*8 + q*2 + (e&1); dest = P + p*256 u32; scale sP[p]
__global__ __launch_bounds__(64) void k_quant4p(const float* __restrict__ in,
                                                u32* __restrict__ P,
                                                float* __restrict__ sP, int m) {
    const int r = blockIdx.x;
    const int l = threadIdx.x;
    const int q = r >> 11, e = r & 2047;
    const int p = (e >> 1) * 16 + m * 8 + q * 2 + (e & 1);
    const float* row = in + (size_t)r * E + l * 32;
    float4 v[8];
    float mx = 0.f;
#pragma unroll
    for (int j = 0; j < 8; ++j) {
        v[j] = *(const float4*)(row + j * 4);
        mx = fmaxf(mx, fmaxf(fmaxf(fabsf(v[j].x), fabsf(v[j].y)),
                             fmaxf(fabsf(v[j].z), fabsf(v[j].w))));
    }
#pragma unroll
    for (int off = 32; off > 0; off >>= 1) mx = fmaxf(mx, __shfl_xor(mx, off));
    mx = fmaxf(mx, 1e-30f);
    const float inv = 7.f / mx;
    float fv[32];
#pragma unroll
    for (int j = 0; j < 8; ++j) {
        fv[4 * j] = v[j].x;
        fv[4 * j + 1] = v[j].y;
        fv[4 * j + 2] = v[j].z;
        fv[4 * j + 3] = v[j].w;
    }
    u32 pk[4] = {0u, 0u, 0u, 0u};
#pragma unroll
    for (int i = 0; i < 32; ++i) {
        int qv = (int)rintf(fv[i] * inv);
        qv = qv < -7 ? -7 : (qv > 7 ? 7 : qv);
        pk[i >> 3] |= ((u32)(qv + 8)) << (4 * (i & 7));
    }
    ((uint4*)(P + (size_t)p * 256))[l] = make_uint4(pk[0], pk[1], pk[2], pk[3]);
    if (l == 0) sP[p] = mx / 7.f;
}

// W_outT[e][d] = W_out[d][e]
__global__ void k_transpose_wout(const float* __restrict__ wout, float* __restrict__ woutT) {
    int o = blockIdx.x * blockDim.x + threadIdx.x;
    if (o >= E * 128) return;
    int e = o >> 7, d = o & 127;
    woutT[o] = wout[d * E + e];
}

// bcomb[r] = b_ih0[r]+b_hh0[r]+dot(W_ih0[r],b_out);  bias1[r] = b_ih1[r]+b_hh1[r]
__global__ void k_bcomb(const float* __restrict__ wih0, const float* __restrict__ bout,
                        const float* __restrict__ bih0, const float* __restrict__ bhh0,
                        const float* __restrict__ bih1, const float* __restrict__ bhh1,
                        float* __restrict__ bcomb, float* __restrict__ bias1) {
    int r = blockIdx.x * blockDim.x + threadIdx.x;
    if (r >= 4 * E) return;
    float acc = bih0[r] + bhh0[r];
    const float* w = wih0 + (size_t)r * 128;
#pragma unroll 8
    for (int k = 0; k < 128; ++k) acc = fmaf(w[k], bout[k], acc);
    bcomb[r] = acc;
    bias1[r] = bih1[r] + bhh1[r];
}

// hist[0] = lat, h0buf slot0 = lat, c0 = c1 = 0
__global__ void k_init(const float* __restrict__ lat, float* __restrict__ hist0,
                       float* __restrict__ h0buf0, float* __restrict__ c0,
                       float* __restrict__ c1) {
    int i = blockIdx.x * blockDim.x + threadIdx.x;
    if (i >= E) return;
    float v = lat[i];
    hist0[i] = v;
    h0buf0[i] = v;
    c0[i] = 0.f;
    c1[i] = 0.f;
}

// ---------------- step kernel: one LSTM layer, 2 elements/block ----------------
// block b owns elements e0=2b, e0+1. Packed chunk P[b]: 16 rows x 1KB:
// row p = m*8 + q*2 + j ; m=0 rows dot inA, m=1 rows dot inB.
__global__ __launch_bounds__(64) void k_step4(
    const u32* __restrict__ P, const float* __restrict__ sP,
    const float* __restrict__ inA, const float* __restrict__ inB,
    const float* __restrict__ bias, float* __restrict__ c, float* __restrict__ hout) {
    const int b = blockIdx.x;
    const int l = threadIdx.x;

    // weights first: one contiguous 16KB stream per block, 16 uint4 in flight/lane
    const uint4* wp = (const uint4*)(P + (size_t)b * 4096);
    uint4 w[16];
#pragma unroll
    for (int p = 0; p < 16; ++p) w[p] = wp[p * 64 + l];

    // activations (L2-hot broadcast)
    float4 hA[8], hB[8];
#pragma unroll
    for (int j = 0; j < 8; ++j) {
        hA[j] = *(const float4*)(inA + l * 32 + j * 4);
        hB[j] = *(const float4*)(inB + l * 32 + j * 4);
    }

    const float* sPb = sP + b * 16;
    float g[8];  // g[j*4+q]
#pragma unroll
    for (int i = 0; i < 8; ++i) g[i] = 0.f;

#pragma unroll
    for (int p = 0; p < 16; ++p) {
        const int m = p >> 3, q = (p >> 1) & 3, j = p & 1;
        float acc = 0.f;
        if (m == 0) {
            acc = dot8i4(w[p].x, hA[0], hA[1], acc);
            acc = dot8i4(w[p].y, hA[2], hA[3], acc);
            acc = dot8i4(w[p].z, hA[4], hA[5], acc);
            acc = dot8i4(w[p].w, hA[6], hA[7], acc);
        } else {
            acc = dot8i4(w[p].x, hB[0], hB[1], acc);
            acc = dot8i4(w[p].y, hB[2], hB[3], acc);
            acc = dot8i4(w[p].z, hB[4], hB[5], acc);
            acc = dot8i4(w[p].w, hB[6], hB[7], acc);
        }
        g[j * 4 + q] += wred(acc) * sPb[p];
    }

    if (l == 0) {
#pragma unroll
        for (int j = 0; j < 2; ++j) {
            const int e = 2 * b + j;
            float gi = g[j * 4 + 0] + bias[e];
            float gf = g[j * 4 + 1] + bias[E + e];
            float gg = g[j * 4 + 2] + bias[2 * E + e];
            float go = g[j * 4 + 3] + bias[3 * E + e];
            float cn = fmaf(sigm(gf), c[e], sigm(gi) * tanhf(gg));
            c[e] = cn;
            hout[e] = sigm(go) * tanhf(cn);
        }
    }
}

// ---------------- final output GEMM: out[t] = Wout @ hist[t] + bout ----------------
__global__ __launch_bounds__(128) void k_out(const float* __restrict__ woutT,
                                             const float* __restrict__ hist,
                                             const float* __restrict__ bout,
                                             float* __restrict__ out) {
    __shared__ float h[E];
    int t = blockIdx.x, d = threadIdx.x;
    for (int i = d; i < E; i += 128) h[i] = hist[(size_t)t * E + i];
    __syncthreads();
    float acc0 = bout[d], acc1 = 0.f;
#pragma unroll 4
    for (int k = 0; k < E; k += 2) {
        acc0 = fmaf(woutT[k * 128 + d], h[k], acc0);
        acc1 = fmaf(woutT[(k + 1) * 128 + d], h[k + 1], acc1);
    }
    out[t * 128 + d] = acc0 + acc1;
}

extern "C" void kernel_launch(void* const* d_in, const int* in_sizes, int n_in,
                              void* d_out, int out_size, void* d_ws, size_t ws_size,
                              hipStream_t stream) {
    const float* lat = (const float*)d_in[0];
    const float* wih0 = (const float*)d_in[1];
    const float* whh0 = (const float*)d_in[2];
    const float* bih0 = (const float*)d_in[3];
    const float* bhh0 = (const float*)d_in[4];
    const float* wih1 = (const float*)d_in[5];
    const float* whh1 = (const float*)d_in[6];
    const float* bih1 = (const float*)d_in[7];
    const float* bhh1 = (const float*)d_in[8];
    const float* wout = (const float*)d_in[9];
    const float* bout = (const float*)d_in[10];

    const size_t PB4 = (size_t)16384 * 1024;  // 16.8 MB packed per layer kernel
    char* p = (char*)d_ws;
    u32* PA = (u32*)p;  p += PB4;   // layer0: m0=Qcomb (xh1), m1=Qhh0 (xh0)
    u32* PBf = (u32*)p; p += PB4;   // layer1: m0=Qih1 (xh0), m1=Qhh1 (xh1)
    float* sPA = (float*)p; p += (size_t)16384 * 4;
    float* sPB = (float*)p; p += (size_t)16384 * 4;
    float* WcF = (float*)p; p += (size_t)4 * E * E * 4;  // 67 MB temp
    float* woutT = (float*)p; p += (size_t)E * 128 * 4;
    float* bcomb = (float*)p; p += (size_t)4 * E * 4;
    float* bias1 = (float*)p; p += (size_t)4 * E * 4;
    float* hist = (float*)p;  p += (size_t)T_STEPS * E * 4;
    float* h0buf = (float*)p; p += (size_t)2 * E * 4;
    float* c0 = (float*)p;    p += (size_t)E * 4;
    float* c1 = (float*)p;    p += (size_t)E * 4;

    k_wcomb<<<dim3(8, 1024), 256, 0, stream>>>(wih0, wout, WcF);
    k_quant4p<<<4 * E, 64, 0, stream>>>(WcF, PA, sPA, 0);
    k_quant4p<<<4 * E, 64, 0, stream>>>(whh0, PA, sPA, 1);
    k_quant4p<<<4 * E, 64, 0, stream>>>(wih1, PBf, sPB, 0);
    k_quant4p<<<4 * E, 64, 0, stream>>>(whh1, PBf, sPB, 1);
    k_transpose_wout<<<(E * 128 + 255) / 256, 256, 0, stream>>>(wout, woutT);
    k_bcomb<<<(4 * E + 255) / 256, 256, 0, stream>>>(wih0, bout, bih0, bhh0, bih1, bhh1,
                                                     bcomb, bias1);
    k_init<<<(E + 255) / 256, 256, 0, stream>>>(lat, hist, h0buf, c0, c1);

    for (int s = 1; s < T_STEPS; ++s) {
        const float* h1p = hist + (size_t)(s - 1) * E;
        const float* h0p = h0buf + (size_t)((s - 1) & 1) * E;
        float* h0n = h0buf + (size_t)(s & 1) * E;
        float* h1n = hist + (size_t)s * E;
        // layer 0: inA = h1(s-1) (Qcomb), inB = h0(s-1) (Qhh0)
        k_step4<<<E / 2, 64, 0, stream>>>(PA, sPA, h1p, h0p, bcomb, c0, h0n);
        // layer 1: inA = h0(s) (Qih1), inB = h1(s-1) (Qhh1)
        k_step4<<<E / 2, 64, 0, stream>>>(PBf, sPB, h0n, h1p, bias1, c1, h1n);
    }

    k_out<<<T_STEPS, 128, 0, stream>>>(woutT, hist, bout, (float*)d_out);
}

// Round 14
// 8468.842 us; speedup vs baseline: 1.2205x; 1.2205x over previous
//
#include <hip/hip_runtime.h>
#include <hip/hip_fp16.h>

typedef unsigned short u16;
typedef unsigned int u32;

#define E 2048
#define T_STEPS 512

// ---------------- helpers ----------------
// dequant 8 int4 (offset-8 nibbles) from one u32 against 8 h-values
__device__ __forceinline__ float dot8i4(u32 v, float4 a, float4 b, float acc) {
    acc = fmaf((float)((int)(v & 15u) - 8), a.x, acc);
    acc = fmaf((float)((int)((v >> 4) & 15u) - 8), a.y, acc);
    acc = fmaf((float)((int)((v >> 8) & 15u) - 8), a.z, acc);
    acc = fmaf((float)((int)((v >> 12) & 15u) - 8), a.w, acc);
    acc = fmaf((float)((int)((v >> 16) & 15u) - 8), b.x, acc);
    acc = fmaf((float)((int)((v >> 20) & 15u) - 8), b.y, acc);
    acc = fmaf((float)((int)((v >> 24) & 15u) - 8), b.z, acc);
    acc = fmaf((float)((int)(v >> 28) - 8), b.w, acc);
    return acc;
}
__device__ __forceinline__ float wred(float t) {
#pragma unroll
    for (int off = 32; off > 0; off >>= 1) t += __shfl_xor(t, off);
    return t;
}
__device__ __forceinline__ float sigm(float v) { return 1.f / (1.f + expf(-v)); }

// load 4 fp16 elems at h16 + idx (8B, wave-coalesced) -> float4
__device__ __forceinline__ float4 ld4h(const __half* __restrict__ h16, int idx) {
    uint2 u = *(const uint2*)(h16 + idx);
    __half2 p0 = *reinterpret_cast<const __half2*>(&u.x);
    __half2 p1 = *reinterpret_cast<const __half2*>(&u.y);
    float2 f0 = __half22float2(p0);
    float2 f1 = __half22float2(p1);
    return make_float4(f0.x, f0.y, f1.x, f1.y);
}

// ---------------- prep kernels ----------------

// W_comb[r][c] = sum_k W_ih0[r][k] * W_out[k][c]  (fp32; 8192 x 2048)
__global__ __launch_bounds__(256) void k_wcomb(const float* __restrict__ wih0,
                                               const float* __restrict__ wout,
                                               float* __restrict__ wc) {
    __shared__ float a[8 * 128];
    int r0 = blockIdx.y * 8;
    int c = blockIdx.x * 256 + threadIdx.x;
    for (int i = threadIdx.x; i < 8 * 128; i += 256) a[i] = wih0[r0 * 128 + i];
    __syncthreads();
    float acc[8] = {0.f, 0.f, 0.f, 0.f, 0.f, 0.f, 0.f, 0.f};
    for (int k = 0; k < 128; ++k) {
        float b = wout[k * E + c];
#pragma unroll
        for (int j = 0; j < 8; ++j) acc[j] = fmaf(a[j * 128 + k], b, acc[j]);
    }
#pragma unroll
    for (int j = 0; j < 8; ++j) wc[(size_t)(r0 + j) * E + c] = acc[j];
}

// per-row int4 quantization, block-packed + lane-coalesced layout.
// input row r of 4ExE: q = r>>11, e = r&2047; packed row p = e*8 + m*4 + q.
// lane l covers elems {j*256 + l*4 .. +3}, j=0..7; u32 k holds groups 2k,2k+1.
__global__ __launch_bounds__(64) void k_quant4p(const float* __restrict__ in,
                                                u32* __restrict__ P,
                                                float* __restrict__ sP, int m) {
    const int r = blockIdx.x;
    const int l = threadIdx.x;
    const int q = r >> 11, e = r & 2047;
    const int p = e * 8 + m * 4 + q;
    const float* row = in + (size_t)r * E;
    float4 v[8];
    float mx = 0.f;
#pragma unroll
    for (int j = 0; j < 8; ++j) {
        v[j] = *(const float4*)(row + j * 256 + l * 4);
        mx = fmaxf(mx, fmaxf(fmaxf(fabsf(v[j].x), fabsf(v[j].y)),
                             fmaxf(fabsf(v[j].z), fabsf(v[j].w))));
    }
#pragma unroll
    for (int off = 32; off > 0; off >>= 1) mx = fmaxf(mx, __shfl_xor(mx, off));
    mx = fmaxf(mx, 1e-30f);
    const float inv = 7.f / mx;
    const float* vf = (const float*)v;
    u32 pk[4];
#pragma unroll
    for (int k = 0; k < 4; ++k) {
        u32 acc = 0u;
#pragma unroll
        for (int i = 0; i < 8; ++i) {
            const int j = 2 * k + (i >> 2);
            float x = vf[j * 4 + (i & 3)];
            int qv = (int)rintf(x * inv);
            qv = qv < -7 ? -7 : (qv > 7 ? 7 : qv);
            acc |= ((u32)(qv + 8)) << (4 * i);
        }
        pk[k] = acc;
    }
    ((uint4*)(P + (size_t)p * 256))[l] = make_uint4(pk[0], pk[1], pk[2], pk[3]);
    if (l == 0) sP[p] = mx / 7.f;
}

// W_outT[e][d] = W_out[d][e]
__global__ void k_transpose_wout(const float* __restrict__ wout, float* __restrict__ woutT) {
    int o = blockIdx.x * blockDim.x + threadIdx.x;
    if (o >= E * 128) return;
    int e = o >> 7, d = o & 127;
    woutT[o] = wout[d * E + e];
}

// bcomb[r] = b_ih0[r]+b_hh0[r]+dot(W_ih0[r],b_out);  bias1[r] = b_ih1[r]+b_hh1[r]
__global__ void k_bcomb(const float* __restrict__ wih0, const float* __restrict__ bout,
                        const float* __restrict__ bih0, const float* __restrict__ bhh0,
                        const float* __restrict__ bih1, const float* __restrict__ bhh1,
                        float* __restrict__ bcomb, float* __restrict__ bias1) {
    int r = blockIdx.x * blockDim.x + threadIdx.x;
    if (r >= 4 * E) return;
    float acc = bih0[r] + bhh0[r];
    const float* w = wih0 + (size_t)r * 128;
#pragma unroll 8
    for (int k = 0; k < 128; ++k) acc = fmaf(w[k], bout[k], acc);
    bcomb[r] = acc;
    bias1[r] = bih1[r] + bhh1[r];
}

// hist[0] = lat (fp16), h0buf slot0 = lat (fp16), c0 = c1 = 0
__global__ void k_init(const float* __restrict__ lat, __half* __restrict__ hist0,
                       __half* __restrict__ h0buf0, float* __restrict__ c0,
                       float* __restrict__ c1) {
    int i = blockIdx.x * blockDim.x + threadIdx.x;
    if (i >= E) return;
    __half v = __float2half(lat[i]);
    hist0[i] = v;
    h0buf0[i] = v;
    c0[i] = 0.f;
    c1[i] = 0.f;
}

// ---------------- step kernel: one LSTM layer, 1 elem/block, fp16 acts ----------------
// block e owns packed chunk P + e*2048 u32 (8 rows x 1KB): row p' = m*4 + q.
// m=0 rows dot inA, m=1 rows dot inB.
__global__ __launch_bounds__(64) void k_stepq(
    const u32* __restrict__ P, const float* __restrict__ sP,
    const __half* __restrict__ inA, const __half* __restrict__ inB,
    const float* __restrict__ bias, float* __restrict__ c,
    __half* __restrict__ hout) {
    const int e = blockIdx.x;
    const int l = threadIdx.x;

    // activations first (depend on previous kernel; wave-coalesced 512B/instr)
    float4 hA[8], hB[8];
#pragma unroll
    for (int j = 0; j < 8; ++j) {
        hA[j] = ld4h(inA, j * 256 + l * 4);
        hB[j] = ld4h(inB, j * 256 + l * 4);
    }

    // weights: contiguous 8KB chunk, 8 uint4 in flight/lane
    const uint4* wp = (const uint4*)(P + (size_t)e * 2048);
    uint4 w[8];
#pragma unroll
    for (int p = 0; p < 8; ++p) w[p] = wp[p * 64 + l];

    const float* sPe = sP + e * 8;
    float g[4] = {0.f, 0.f, 0.f, 0.f};
#pragma unroll
    for (int p = 0; p < 8; ++p) {
        const int m = p >> 2, q = p & 3;
        float acc = 0.f;
        if (m == 0) {
            acc = dot8i4(w[p].x, hA[0], hA[1], acc);
            acc = dot8i4(w[p].y, hA[2], hA[3], acc);
            acc = dot8i4(w[p].z, hA[4], hA[5], acc);
            acc = dot8i4(w[p].w, hA[6], hA[7], acc);
        } else {
            acc = dot8i4(w[p].x, hB[0], hB[1], acc);
            acc = dot8i4(w[p].y, hB[2], hB[3], acc);
            acc = dot8i4(w[p].z, hB[4], hB[5], acc);
            acc = dot8i4(w[p].w, hB[6], hB[7], acc);
        }
        g[q] += wred(acc) * sPe[p];
    }

    if (l == 0) {
        float gi = g[0] + bias[e];
        float gf = g[1] + bias[E + e];
        float gg = g[2] + bias[2 * E + e];
        float go = g[3] + bias[3 * E + e];
        float cn = fmaf(sigm(gf), c[e], sigm(gi) * tanhf(gg));
        c[e] = cn;
        hout[e] = __float2half(sigm(go) * tanhf(cn));
    }
}

// ---------------- final output GEMM: out[t] = Wout @ hist[t] + bout ----------------
__global__ __launch_bounds__(128) void k_out(const float* __restrict__ woutT,
                                             const __half* __restrict__ hist,
                                             const float* __restrict__ bout,
                                             float* __restrict__ out) {
    __shared__ float h[E];
    int t = blockIdx.x, d = threadIdx.x;
    for (int i = d; i < E; i += 128) h[i] = __half2float(hist[(size_t)t * E + i]);
    __syncthreads();
    float acc0 = bout[d], acc1 = 0.f;
#pragma unroll 4
    for (int k = 0; k < E; k += 2) {
        acc0 = fmaf(woutT[k * 128 + d], h[k], acc0);
        acc1 = fmaf(woutT[(k + 1) * 128 + d], h[k + 1], acc1);
    }
    out[t * 128 + d] = acc0 + acc1;
}

extern "C" void kernel_launch(void* const* d_in, const int* in_sizes, int n_in,
                              void* d_out, int out_size, void* d_ws, size_t ws_size,
                              hipStream_t stream) {
    const float* lat = (const float*)d_in[0];
    const float* wih0 = (const float*)d_in[1];
    const float* whh0 = (const float*)d_in[2];
    const float* bih0 = (const float*)d_in[3];
    const float* bhh0 = (const float*)d_in[4];
    const float* wih1 = (const float*)d_in[5];
    const float* whh1 = (const float*)d_in[6];
    const float* bih1 = (const float*)d_in[7];
    const float* bhh1 = (const float*)d_in[8];
    const float* wout = (const float*)d_in[9];
    const float* bout = (const float*)d_in[10];

    const size_t PB4 = (size_t)2048 * 8192;  // 16.8 MB packed per layer
    char* p = (char*)d_ws;
    u32* PA = (u32*)p;  p += PB4;   // layer0: m0=Qcomb (x h1), m1=Qhh0 (x h0)
    u32* PBf = (u32*)p; p += PB4;   // layer1: m0=Qih1 (x h0), m1=Qhh1 (x h1)
    float* sPA = (float*)p; p += (size_t)16384 * 4;
    float* sPB = (float*)p; p += (size_t)16384 * 4;
    float* WcF = (float*)p; p += (size_t)4 * E * E * 4;  // 67 MB temp
    float* woutT = (float*)p; p += (size_t)E * 128 * 4;
    float* bcomb = (float*)p; p += (size_t)4 * E * 4;
    float* bias1 = (float*)p; p += (size_t)4 * E * 4;
    __half* hist = (__half*)p;  p += (size_t)T_STEPS * E * 2;
    __half* h0buf = (__half*)p; p += (size_t)2 * E * 2;
    float* c0 = (float*)p;    p += (size_t)E * 4;
    float* c1 = (float*)p;    p += (size_t)E * 4;

    k_wcomb<<<dim3(8, 1024), 256, 0, stream>>>(wih0, wout, WcF);
    k_quant4p<<<4 * E, 64, 0, stream>>>(WcF, PA, sPA, 0);
    k_quant4p<<<4 * E, 64, 0, stream>>>(whh0, PA, sPA, 1);
    k_quant4p<<<4 * E, 64, 0, stream>>>(wih1, PBf, sPB, 0);
    k_quant4p<<<4 * E, 64, 0, stream>>>(whh1, PBf, sPB, 1);
    k_transpose_wout<<<(E * 128 + 255) / 256, 256, 0, stream>>>(wout, woutT);
    k_bcomb<<<(4 * E + 255) / 256, 256, 0, stream>>>(wih0, bout, bih0, bhh0, bih1, bhh1,
                                                     bcomb, bias1);
    k_init<<<(E + 255) / 256, 256, 0, stream>>>(lat, hist, h0buf, c0, c1);

    for (int s = 1; s < T_STEPS; ++s) {
        const __half* h1p = hist + (size_t)(s - 1) * E;
        const __half* h0p = h0buf + (size_t)((s - 1) & 1) * E;
        __half* h0n = h0buf + (size_t)(s & 1) * E;
        __half* h1n = hist + (size_t)s * E;
        // layer 0: inA = h1(s-1) (Qcomb), inB = h0(s-1) (Qhh0)
        k_stepq<<<E, 64, 0, stream>>>(PA, sPA, h1p, h0p, bcomb, c0, h0n);
        // layer 1: inA = h0(s) (Qih1), inB = h1(s-1) (Qhh1)
        k_stepq<<<E, 64, 0, stream>>>(PBf, sPB, h0n, h1p, bias1, c1, h1n);
    }

    k_out<<<T_STEPS, 128, 0, stream>>>(woutT, hist, bout, (float*)d_out);
}

// Round 15
// 8134.552 us; speedup vs baseline: 1.2707x; 1.0411x over previous
//
#include <hip/hip_runtime.h>
#include <hip/hip_fp16.h>

typedef unsigned short u16;
typedef unsigned int u32;

#define E 2048
#define T_STEPS 512

// ---------------- helpers ----------------
// dequant 8 int4 (offset-8 nibbles) from one u32 against 8 h-values
__device__ __forceinline__ float dot8i4(u32 v, float4 a, float4 b, float acc) {
    acc = fmaf((float)((int)(v & 15u) - 8), a.x, acc);
    acc = fmaf((float)((int)((v >> 4) & 15u) - 8), a.y, acc);
    acc = fmaf((float)((int)((v >> 8) & 15u) - 8), a.z, acc);
    acc = fmaf((float)((int)((v >> 12) & 15u) - 8), a.w, acc);
    acc = fmaf((float)((int)((v >> 16) & 15u) - 8), b.x, acc);
    acc = fmaf((float)((int)((v >> 20) & 15u) - 8), b.y, acc);
    acc = fmaf((float)((int)((v >> 24) & 15u) - 8), b.z, acc);
    acc = fmaf((float)((int)(v >> 28) - 8), b.w, acc);
    return acc;
}
__device__ __forceinline__ float wred(float t) {
#pragma unroll
    for (int off = 32; off > 0; off >>= 1) t += __shfl_xor(t, off);
    return t;
}
__device__ __forceinline__ float sigm(float v) { return 1.f / (1.f + expf(-v)); }

// load 4 fp16 elems at h16 + idx (8B, wave-coalesced) -> float4
__device__ __forceinline__ float4 ld4h(const __half* __restrict__ h16, int idx) {
    uint2 u = *(const uint2*)(h16 + idx);
    __half2 p0 = *reinterpret_cast<const __half2*>(&u.x);
    __half2 p1 = *reinterpret_cast<const __half2*>(&u.y);
    float2 f0 = __half22float2(p0);
    float2 f1 = __half22float2(p1);
    return make_float4(f0.x, f0.y, f1.x, f1.y);
}

// ---------------- prep kernels ----------------

// W_comb[r][c] = sum_k W_ih0[r][k] * W_out[k][c]  (fp32; 8192 x 2048)
__global__ __launch_bounds__(256) void k_wcomb(const float* __restrict__ wih0,
                                               const float* __restrict__ wout,
                                               float* __restrict__ wc) {
    __shared__ float a[8 * 128];
    int r0 = blockIdx.y * 8;
    int c = blockIdx.x * 256 + threadIdx.x;
    for (int i = threadIdx.x; i < 8 * 128; i += 256) a[i] = wih0[r0 * 128 + i];
    __syncthreads();
    float acc[8] = {0.f, 0.f, 0.f, 0.f, 0.f, 0.f, 0.f, 0.f};
    for (int k = 0; k < 128; ++k) {
        float b = wout[k * E + c];
#pragma unroll
        for (int j = 0; j < 8; ++j) acc[j] = fmaf(a[j * 128 + k], b, acc[j]);
    }
#pragma unroll
    for (int j = 0; j < 8; ++j) wc[(size_t)(r0 + j) * E + c] = acc[j];
}

// per-row int4 quantization, block-packed + lane-coalesced layout.
// input row r of 4ExE: q = r>>11, e = r&2047; packed row p = e*8 + m*4 + q.
// lane l covers elems {j*256 + l*4 .. +3}, j=0..7; u32 k holds groups 2k,2k+1.
__global__ __launch_bounds__(64) void k_quant4p(const float* __restrict__ in,
                                                u32* __restrict__ P,
                                                float* __restrict__ sP, int m) {
    const int r = blockIdx.x;
    const int l = threadIdx.x;
    const int q = r >> 11, e = r & 2047;
    const int p = e * 8 + m * 4 + q;
    const float* row = in + (size_t)r * E;
    float4 v[8];
    float mx = 0.f;
#pragma unroll
    for (int j = 0; j < 8; ++j) {
        v[j] = *(const float4*)(row + j * 256 + l * 4);
        mx = fmaxf(mx, fmaxf(fmaxf(fabsf(v[j].x), fabsf(v[j].y)),
                             fmaxf(fabsf(v[j].z), fabsf(v[j].w))));
    }
#pragma unroll
    for (int off = 32; off > 0; off >>= 1) mx = fmaxf(mx, __shfl_xor(mx, off));
    mx = fmaxf(mx, 1e-30f);
    const float inv = 7.f / mx;
    const float* vf = (const float*)v;
    u32 pk[4];
#pragma unroll
    for (int k = 0; k < 4; ++k) {
        u32 acc = 0u;
#pragma unroll
        for (int i = 0; i < 8; ++i) {
            const int j = 2 * k + (i >> 2);
            float x = vf[j * 4 + (i & 3)];
            int qv = (int)rintf(x * inv);
            qv = qv < -7 ? -7 : (qv > 7 ? 7 : qv);
            acc |= ((u32)(qv + 8)) << (4 * i);
        }
        pk[k] = acc;
    }
    ((uint4*)(P + (size_t)p * 256))[l] = make_uint4(pk[0], pk[1], pk[2], pk[3]);
    if (l == 0) sP[p] = mx / 7.f;
}

// W_outT[e][d] = W_out[d][e]
__global__ void k_transpose_wout(const float* __restrict__ wout, float* __restrict__ woutT) {
    int o = blockIdx.x * blockDim.x + threadIdx.x;
    if (o >= E * 128) return;
    int e = o >> 7, d = o & 127;
    woutT[o] = wout[d * E + e];
}

// bcomb[r] = b_ih0[r]+b_hh0[r]+dot(W_ih0[r],b_out);  bias1[r] = b_ih1[r]+b_hh1[r]
__global__ void k_bcomb(const float* __restrict__ wih0, const float* __restrict__ bout,
                        const float* __restrict__ bih0, const float* __restrict__ bhh0,
                        const float* __restrict__ bih1, const float* __restrict__ bhh1,
                        float* __restrict__ bcomb, float* __restrict__ bias1) {
    int r = blockIdx.x * blockDim.x + threadIdx.x;
    if (r >= 4 * E) return;
    float acc = bih0[r] + bhh0[r];
    const float* w = wih0 + (size_t)r * 128;
#pragma unroll 8
    for (int k = 0; k < 128; ++k) acc = fmaf(w[k], bout[k], acc);
    bcomb[r] = acc;
    bias1[r] = bih1[r] + bhh1[r];
}

// hist[0] = lat (fp16), h0buf slot0 = lat (fp16), c0 = c1 = 0
__global__ void k_init(const float* __restrict__ lat, __half* __restrict__ hist0,
                       __half* __restrict__ h0buf0, float* __restrict__ c0,
                       float* __restrict__ c1) {
    int i = blockIdx.x * blockDim.x + threadIdx.x;
    if (i >= E) return;
    __half v = __float2half(lat[i]);
    hist0[i] = v;
    h0buf0[i] = v;
    c0[i] = 0.f;
    c1[i] = 0.f;
}

// ---------------- step kernel: one LSTM layer, 4 elems/block, 4 indep waves ----------
// wave w of block b owns element e = 4b + w; packed chunk P + e*2048 u32
// (8 rows x 1KB): row p' = m*4 + q. m=0 rows dot inA, m=1 rows dot inB.
__global__ __launch_bounds__(256) void k_stepq(
    const u32* __restrict__ P, const float* __restrict__ sP,
    const __half* __restrict__ inA, const __half* __restrict__ inB,
    const float* __restrict__ bias, float* __restrict__ c,
    __half* __restrict__ hout) {
    const int e = blockIdx.x * 4 + (threadIdx.x >> 6);
    const int l = threadIdx.x & 63;

    // activations first (depend on previous kernel; wave-coalesced 512B/instr)
    float4 hA[8], hB[8];
#pragma unroll
    for (int j = 0; j < 8; ++j) {
        hA[j] = ld4h(inA, j * 256 + l * 4);
        hB[j] = ld4h(inB, j * 256 + l * 4);
    }

    // weights: contiguous 8KB chunk per wave, 8 uint4 in flight/lane
    const uint4* wp = (const uint4*)(P + (size_t)e * 2048);
    uint4 w[8];
#pragma unroll
    for (int p = 0; p < 8; ++p) w[p] = wp[p * 64 + l];

    const float* sPe = sP + e * 8;
    float g[4];
#pragma unroll
    for (int q = 0; q < 4; ++q) {
        float accA = 0.f, accB = 0.f;
        accA = dot8i4(w[q].x, hA[0], hA[1], accA);
        accA = dot8i4(w[q].y, hA[2], hA[3], accA);
        accA = dot8i4(w[q].z, hA[4], hA[5], accA);
        accA = dot8i4(w[q].w, hA[6], hA[7], accA);
        accB = dot8i4(w[4 + q].x, hB[0], hB[1], accB);
        accB = dot8i4(w[4 + q].y, hB[2], hB[3], accB);
        accB = dot8i4(w[4 + q].z, hB[4], hB[5], accB);
        accB = dot8i4(w[4 + q].w, hB[6], hB[7], accB);
        g[q] = wred(accA * sPe[q] + accB * sPe[4 + q]);  // one reduce per gate
    }

    if (l == 0) {
        float gi = g[0] + bias[e];
        float gf = g[1] + bias[E + e];
        float gg = g[2] + bias[2 * E + e];
        float go = g[3] + bias[3 * E + e];
        float cn = fmaf(sigm(gf), c[e], sigm(gi) * tanhf(gg));
        c[e] = cn;
        hout[e] = __float2half(sigm(go) * tanhf(cn));
    }
}

// ---------------- final output GEMM: out[t] = Wout @ hist[t] + bout ----------------
__global__ __launch_bounds__(128) void k_out(const float* __restrict__ woutT,
                                             const __half* __restrict__ hist,
                                             const float* __restrict__ bout,
                                             float* __restrict__ out) {
    __shared__ float h[E];
    int t = blockIdx.x, d = threadIdx.x;
    for (int i = d; i < E; i += 128) h[i] = __half2float(hist[(size_t)t * E + i]);
    __syncthreads();
    float acc0 = bout[d], acc1 = 0.f;
#pragma unroll 4
    for (int k = 0; k < E; k += 2) {
        acc0 = fmaf(woutT[k * 128 + d], h[k], acc0);
        acc1 = fmaf(woutT[(k + 1) * 128 + d], h[k + 1], acc1);
    }
    out[t * 128 + d] = acc0 + acc1;
}

extern "C" void kernel_launch(void* const* d_in, const int* in_sizes, int n_in,
                              void* d_out, int out_size, void* d_ws, size_t ws_size,
                              hipStream_t stream) {
    const float* lat = (const float*)d_in[0];
    const float* wih0 = (const float*)d_in[1];
    const float* whh0 = (const float*)d_in[2];
    const float* bih0 = (const float*)d_in[3];
    const float* bhh0 = (const float*)d_in[4];
    const float* wih1 = (const float*)d_in[5];
    const float* whh1 = (const float*)d_in[6];
    const float* bih1 = (const float*)d_in[7];
    const float* bhh1 = (const float*)d_in[8];
    const float* wout = (const float*)d_in[9];
    const float* bout = (const float*)d_in[10];

    const size_t PB4 = (size_t)2048 * 8192;  // 16.8 MB packed per layer
    char* p = (char*)d_ws;
    u32* PA = (u32*)p;  p += PB4;   // layer0: m0=Qcomb (x h1), m1=Qhh0 (x h0)
    u32* PBf = (u32*)p; p += PB4;   // layer1: m0=Qih1 (x h0), m1=Qhh1 (x h1)
    float* sPA = (float*)p; p += (size_t)16384 * 4;
    float* sPB = (float*)p; p += (size_t)16384 * 4;
    float* WcF = (float*)p; p += (size_t)4 * E * E * 4;  // 67 MB temp
    float* woutT = (float*)p; p += (size_t)E * 128 * 4;
    float* bcomb = (float*)p; p += (size_t)4 * E * 4;
    float* bias1 = (float*)p; p += (size_t)4 * E * 4;
    __half* hist = (__half*)p;  p += (size_t)T_STEPS * E * 2;
    __half* h0buf = (__half*)p; p += (size_t)2 * E * 2;
    float* c0 = (float*)p;    p += (size_t)E * 4;
    float* c1 = (float*)p;    p += (size_t)E * 4;

    k_wcomb<<<dim3(8, 1024), 256, 0, stream>>>(wih0, wout, WcF);
    k_quant4p<<<4 * E, 64, 0, stream>>>(WcF, PA, sPA, 0);
    k_quant4p<<<4 * E, 64, 0, stream>>>(whh0, PA, sPA, 1);
    k_quant4p<<<4 * E, 64, 0, stream>>>(wih1, PBf, sPB, 0);
    k_quant4p<<<4 * E, 64, 0, stream>>>(whh1, PBf, sPB, 1);
    k_transpose_wout<<<(E * 128 + 255) / 256, 256, 0, stream>>>(wout, woutT);
    k_bcomb<<<(4 * E + 255) / 256, 256, 0, stream>>>(wih0, bout, bih0, bhh0, bih1, bhh1,
                                                     bcomb, bias1);
    k_init<<<(E + 255) / 256, 256, 0, stream>>>(lat, hist, h0buf, c0, c1);

    for (int s = 1; s < T_STEPS; ++s) {
        const __half* h1p = hist + (size_t)(s - 1) * E;
        const __half* h0p = h0buf + (size_t)((s - 1) & 1) * E;
        __half* h0n = h0buf + (size_t)(s & 1) * E;
        __half* h1n = hist + (size_t)s * E;
        // layer 0: inA = h1(s-1) (Qcomb), inB = h0(s-1) (Qhh0)
        k_stepq<<<E / 4, 256, 0, stream>>>(PA, sPA, h1p, h0p, bcomb, c0, h0n);
        // layer 1: inA = h0(s) (Qih1), inB = h1(s-1) (Qhh1)
        k_stepq<<<E / 4, 256, 0, stream>>>(PBf, sPB, h0n, h1p, bias1, c1, h1n);
    }

    k_out<<<T_STEPS, 128, 0, stream>>>(woutT, hist, bout, (float*)d_out);
}

// Round 16
// 7737.166 us; speedup vs baseline: 1.3360x; 1.0514x over previous
//
#include <hip/hip_runtime.h>
#include <hip/hip_fp16.h>

typedef unsigned short u16;
typedef unsigned int u32;
typedef unsigned long long u64;

#define E 2048
#define T_STEPS 512

// ---------------- helpers ----------------
// dequant 8 int4 (offset-8 nibbles) from one u32 against 8 h-values
__device__ __forceinline__ float dot8i4(u32 v, float4 a, float4 b, float acc) {
    acc = fmaf((float)((int)(v & 15u) - 8), a.x, acc);
    acc = fmaf((float)((int)((v >> 4) & 15u) - 8), a.y, acc);
    acc = fmaf((float)((int)((v >> 8) & 15u) - 8), a.z, acc);
    acc = fmaf((float)((int)((v >> 12) & 15u) - 8), a.w, acc);
    acc = fmaf((float)((int)((v >> 16) & 15u) - 8), b.x, acc);
    acc = fmaf((float)((int)((v >> 20) & 15u) - 8), b.y, acc);
    acc = fmaf((float)((int)((v >> 24) & 15u) - 8), b.z, acc);
    acc = fmaf((float)((int)(v >> 28) - 8), b.w, acc);
    return acc;
}
// dequant 32 int3 (offset-4) packed in 96-bit (A,B,C) against 32 h-values
__device__ __forceinline__ float dot32i3(u32 A, u32 B, u32 C,
                                         const float4* __restrict__ h, float acc) {
    const u64 AB = ((u64)B << 32) | A;
    const u64 BC = ((u64)C << 32) | B;
    const float* hf = (const float*)h;
#pragma unroll
    for (int i = 0; i < 32; ++i) {
        u32 v;
        if (i <= 20) v = (u32)(AB >> (3 * i)) & 7u;          // compile-time shifts
        else         v = (u32)(BC >> (3 * i - 32)) & 7u;
        acc = fmaf((float)((int)v - 4), hf[i], acc);
    }
    return acc;
}
__device__ __forceinline__ float wred(float t) {
#pragma unroll
    for (int off = 32; off > 0; off >>= 1) t += __shfl_xor(t, off);
    return t;
}
__device__ __forceinline__ float sigm(float v) { return 1.f / (1.f + expf(-v)); }

// load 4 fp16 elems at h16 + idx (8B, wave-coalesced) -> float4
__device__ __forceinline__ float4 ld4h(const __half* __restrict__ h16, int idx) {
    uint2 u = *(const uint2*)(h16 + idx);
    __half2 p0 = *reinterpret_cast<const __half2*>(&u.x);
    __half2 p1 = *reinterpret_cast<const __half2*>(&u.y);
    float2 f0 = __half22float2(p0);
    float2 f1 = __half22float2(p1);
    return make_float4(f0.x, f0.y, f1.x, f1.y);
}

// ---------------- prep kernels ----------------

// W_comb[r][c] = sum_k W_ih0[r][k] * W_out[k][c]  (fp32; 8192 x 2048)
__global__ __launch_bounds__(256) void k_wcomb(const float* __restrict__ wih0,
                                               const float* __restrict__ wout,
                                               float* __restrict__ wc) {
    __shared__ float a[8 * 128];
    int r0 = blockIdx.y * 8;
    int c = blockIdx.x * 256 + threadIdx.x;
    for (int i = threadIdx.x; i < 8 * 128; i += 256) a[i] = wih0[r0 * 128 + i];
    __syncthreads();
    float acc[8] = {0.f, 0.f, 0.f, 0.f, 0.f, 0.f, 0.f, 0.f};
    for (int k = 0; k < 128; ++k) {
        float b = wout[k * E + c];
#pragma unroll
        for (int j = 0; j < 8; ++j) acc[j] = fmaf(a[j * 128 + k], b, acc[j]);
    }
#pragma unroll
    for (int j = 0; j < 8; ++j) wc[(size_t)(r0 + j) * E + c] = acc[j];
}

// int4 quantization, elem-packed: input row r (q=r>>11, e=r&2047) -> packed row
// p = e*4+q (256 u32); lane l covers elems {j*256+l*4..+3}; u32 k holds groups 2k,2k+1
__global__ __launch_bounds__(64) void k_quant4p(const float* __restrict__ in,
                                                u32* __restrict__ P,
                                                float* __restrict__ sP) {
    const int r = blockIdx.x;
    const int l = threadIdx.x;
    const int q = r >> 11, e = r & 2047;
    const int p = e * 4 + q;
    const float* row = in + (size_t)r * E;
    float4 v[8];
    float mx = 0.f;
#pragma unroll
    for (int j = 0; j < 8; ++j) {
        v[j] = *(const float4*)(row + j * 256 + l * 4);
        mx = fmaxf(mx, fmaxf(fmaxf(fabsf(v[j].x), fabsf(v[j].y)),
                             fmaxf(fabsf(v[j].z), fabsf(v[j].w))));
    }
#pragma unroll
    for (int off = 32; off > 0; off >>= 1) mx = fmaxf(mx, __shfl_xor(mx, off));
    mx = fmaxf(mx, 1e-30f);
    const float inv = 7.f / mx;
    const float* vf = (const float*)v;
    u32 pk[4];
#pragma unroll
    for (int k = 0; k < 4; ++k) {
        u32 acc = 0u;
#pragma unroll
        for (int i = 0; i < 8; ++i) {
            const int j = 2 * k + (i >> 2);
            float x = vf[j * 4 + (i & 3)];
            int qv = (int)rintf(x * inv);
            qv = qv < -7 ? -7 : (qv > 7 ? 7 : qv);
            acc |= ((u32)(qv + 8)) << (4 * i);
        }
        pk[k] = acc;
    }
    ((uint4*)(P + (size_t)p * 256))[l] = make_uint4(pk[0], pk[1], pk[2], pk[3]);
    if (l == 0) sP[p] = mx / 7.f;
}

// int3 quantization, plane-packed: packed row p = e*4+q occupies 192 u32:
// lane l's 32 values -> 96-bit {A,B,C} stored at [p*192+l], [p*192+64+l], [p*192+128+l]
__global__ __launch_bounds__(64) void k_quant3p(const float* __restrict__ in,
                                                u32* __restrict__ P,
                                                float* __restrict__ sP) {
    const int r = blockIdx.x;
    const int l = threadIdx.x;
    const int q = r >> 11, e = r & 2047;
    const int p = e * 4 + q;
    const float* row = in + (size_t)r * E;
    float4 v[8];
    float mx = 0.f;
#pragma unroll
    for (int j = 0; j < 8; ++j) {
        v[j] = *(const float4*)(row + j * 256 + l * 4);
        mx = fmaxf(mx, fmaxf(fmaxf(fabsf(v[j].x), fabsf(v[j].y)),
                             fmaxf(fabsf(v[j].z), fabsf(v[j].w))));
    }
#pragma unroll
    for (int off = 32; off > 0; off >>= 1) mx = fmaxf(mx, __shfl_xor(mx, off));
    mx = fmaxf(mx, 1e-30f);
    const float inv = 3.f / mx;
    const float* vf = (const float*)v;
    u32 w3[3] = {0u, 0u, 0u};
#pragma unroll
    for (int i = 0; i < 32; ++i) {
        float x = vf[i];
        int qv = (int)rintf(x * inv);
        qv = qv < -3 ? -3 : (qv > 3 ? 3 : qv);
        const u32 u = (u32)(qv + 4);
        const int bit = 3 * i, word = bit >> 5, off = bit & 31;
        w3[word] |= u << off;
        if (off > 29 && word < 2) w3[word + 1] |= u >> (32 - off);
    }
    u32* dst = P + (size_t)p * 192;
    dst[l] = w3[0];
    dst[64 + l] = w3[1];
    dst[128 + l] = w3[2];
    if (l == 0) sP[p] = mx / 3.f;
}

// W_outT[e][d] = W_out[d][e]
__global__ void k_transpose_wout(const float* __restrict__ wout, float* __restrict__ woutT) {
    int o = blockIdx.x * blockDim.x + threadIdx.x;
    if (o >= E * 128) return;
    int e = o >> 7, d = o & 127;
    woutT[o] = wout[d * E + e];
}

// bcomb[r] = b_ih0[r]+b_hh0[r]+dot(W_ih0[r],b_out);  bias1[r] = b_ih1[r]+b_hh1[r]
__global__ void k_bcomb(const float* __restrict__ wih0, const float* __restrict__ bout,
                        const float* __restrict__ bih0, const float* __restrict__ bhh0,
                        const float* __restrict__ bih1, const float* __restrict__ bhh1,
                        float* __restrict__ bcomb, float* __restrict__ bias1) {
    int r = blockIdx.x * blockDim.x + threadIdx.x;
    if (r >= 4 * E) return;
    float acc = bih0[r] + bhh0[r];
    const float* w = wih0 + (size_t)r * 128;
#pragma unroll 8
    for (int k = 0; k < 128; ++k) acc = fmaf(w[k], bout[k], acc);
    bcomb[r] = acc;
    bias1[r] = bih1[r] + bhh1[r];
}

// hist[0] = lat (fp16), h0buf slot0 = lat (fp16), c0 = c1 = 0
__global__ void k_init(const float* __restrict__ lat, __half* __restrict__ hist0,
                       __half* __restrict__ h0buf0, float* __restrict__ c0,
                       float* __restrict__ c1) {
    int i = blockIdx.x * blockDim.x + threadIdx.x;
    if (i >= E) return;
    __half v = __float2half(lat[i]);
    hist0[i] = v;
    h0buf0[i] = v;
    c0[i] = 0.f;
    c1[i] = 0.f;
}

// ---------------- step kernel: one LSTM layer, 4 elems/block, 4 indep waves ----------
// wave w owns elem e = 4b+w. A-matrix int4 (PA + e*1024 u32, rows q*256) dots inA;
// B-matrix int3 (PB + e*768 u32, rows q*192 planes) dots inB.
__global__ __launch_bounds__(256) void k_stepq(
    const u32* __restrict__ PA, const float* __restrict__ sA,
    const u32* __restrict__ PB, const float* __restrict__ sB,
    const __half* __restrict__ inA, const __half* __restrict__ inB,
    const float* __restrict__ bias, float* __restrict__ c,
    __half* __restrict__ hout) {
    const int e = blockIdx.x * 4 + (threadIdx.x >> 6);
    const int l = threadIdx.x & 63;

    // activations first (dependent on previous kernel)
    float4 hA[8], hB[8];
#pragma unroll
    for (int j = 0; j < 8; ++j) {
        hA[j] = ld4h(inA, j * 256 + l * 4);
        hB[j] = ld4h(inB, j * 256 + l * 4);
    }

    // weights: int4 chunk (4 x uint4/lane) + int3 chunk (4 x 3 u32/lane)
    const u32* wp4 = PA + (size_t)e * 1024;
    const u32* wp3 = PB + (size_t)e * 768;
    uint4 w4[4];
    u32 a3[4], b3[4], c3[4];
#pragma unroll
    for (int q = 0; q < 4; ++q) {
        w4[q] = ((const uint4*)(wp4 + q * 256))[l];
        a3[q] = wp3[q * 192 + l];
        b3[q] = wp3[q * 192 + 64 + l];
        c3[q] = wp3[q * 192 + 128 + l];
    }

    const float* sAe = sA + e * 4;
    const float* sBe = sB + e * 4;
    float g[4];
#pragma unroll
    for (int q = 0; q < 4; ++q) {
        float accA = 0.f;
        accA = dot8i4(w4[q].x, hA[0], hA[1], accA);
        accA = dot8i4(w4[q].y, hA[2], hA[3], accA);
        accA = dot8i4(w4[q].z, hA[4], hA[5], accA);
        accA = dot8i4(w4[q].w, hA[6], hA[7], accA);
        float accB = dot32i3(a3[q], b3[q], c3[q], hB, 0.f);
        g[q] = wred(accA * sAe[q] + accB * sBe[q]);
    }

    if (l == 0) {
        float gi = g[0] + bias[e];
        float gf = g[1] + bias[E + e];
        float gg = g[2] + bias[2 * E + e];
        float go = g[3] + bias[3 * E + e];
        float cn = fmaf(sigm(gf), c[e], sigm(gi) * tanhf(gg));
        c[e] = cn;
        hout[e] = __float2half(sigm(go) * tanhf(cn));
    }
}

// ---------------- final output GEMM: out[t] = Wout @ hist[t] + bout ----------------
__global__ __launch_bounds__(128) void k_out(const float* __restrict__ woutT,
                                             const __half* __restrict__ hist,
                                             const float* __restrict__ bout,
                                             float* __restrict__ out) {
    __shared__ float h[E];
    int t = blockIdx.x, d = threadIdx.x;
    for (int i = d; i < E; i += 128) h[i] = __half2float(hist[(size_t)t * E + i]);
    __syncthreads();
    float acc0 = bout[d], acc1 = 0.f;
#pragma unroll 4
    for (int k = 0; k < E; k += 2) {
        acc0 = fmaf(woutT[k * 128 + d], h[k], acc0);
        acc1 = fmaf(woutT[(k + 1) * 128 + d], h[k + 1], acc1);
    }
    out[t * 128 + d] = acc0 + acc1;
}

extern "C" void kernel_launch(void* const* d_in, const int* in_sizes, int n_in,
                              void* d_out, int out_size, void* d_ws, size_t ws_size,
                              hipStream_t stream) {
    const float* lat = (const float*)d_in[0];
    const float* wih0 = (const float*)d_in[1];
    const float* whh0 = (const float*)d_in[2];
    const float* bih0 = (const float*)d_in[3];
    const float* bhh0 = (const float*)d_in[4];
    const float* wih1 = (const float*)d_in[5];
    const float* whh1 = (const float*)d_in[6];
    const float* bih1 = (const float*)d_in[7];
    const float* bhh1 = (const float*)d_in[8];
    const float* wout = (const float*)d_in[9];
    const float* bout = (const float*)d_in[10];

    const size_t P4B = (size_t)E * 4096;  // int4: 8.39 MB (4 rows x 1KB x 2048 elems)
    const size_t P3B = (size_t)E * 3072;  // int3: 6.29 MB (4 rows x 768B x 2048 elems)
    char* p = (char*)d_ws;
    u32* PA0 = (u32*)p; p += P4B;  // layer0 cross: Qcomb (x h1)
    u32* PB0 = (u32*)p; p += P3B;  // layer0 recur: Qhh0 (x h0)
    u32* PA1 = (u32*)p; p += P4B;  // layer1 cross: Qih1 (x h0)
    u32* PB1 = (u32*)p; p += P3B;  // layer1 recur: Qhh1 (x h1)
    float* sA0 = (float*)p; p += (size_t)4 * E * 4;
    float* sB0 = (float*)p; p += (size_t)4 * E * 4;
    float* sA1 = (float*)p; p += (size_t)4 * E * 4;
    float* sB1 = (float*)p; p += (size_t)4 * E * 4;
    float* WcF = (float*)p; p += (size_t)4 * E * E * 4;  // 67 MB temp
    float* woutT = (float*)p; p += (size_t)E * 128 * 4;
    float* bcomb = (float*)p; p += (size_t)4 * E * 4;
    float* bias1 = (float*)p; p += (size_t)4 * E * 4;
    __half* hist = (__half*)p;  p += (size_t)T_STEPS * E * 2;
    __half* h0buf = (__half*)p; p += (size_t)2 * E * 2;
    float* c0 = (float*)p;    p += (size_t)E * 4;
    float* c1 = (float*)p;    p += (size_t)E * 4;

    k_wcomb<<<dim3(8, 1024), 256, 0, stream>>>(wih0, wout, WcF);
    k_quant4p<<<4 * E, 64, 0, stream>>>(WcF, PA0, sA0);
    k_quant3p<<<4 * E, 64, 0, stream>>>(whh0, PB0, sB0);
    k_quant4p<<<4 * E, 64, 0, stream>>>(wih1, PA1, sA1);
    k_quant3p<<<4 * E, 64, 0, stream>>>(whh1, PB1, sB1);
    k_transpose_wout<<<(E * 128 + 255) / 256, 256, 0, stream>>>(wout, woutT);
    k_bcomb<<<(4 * E + 255) / 256, 256, 0, stream>>>(wih0, bout, bih0, bhh0, bih1, bhh1,
                                                     bcomb, bias1);
    k_init<<<(E + 255) / 256, 256, 0, stream>>>(lat, hist, h0buf, c0, c1);

    for (int s = 1; s < T_STEPS; ++s) {
        const __half* h1p = hist + (size_t)(s - 1) * E;
        const __half* h0p = h0buf + (size_t)((s - 1) & 1) * E;
        __half* h0n = h0buf + (size_t)(s & 1) * E;
        __half* h1n = hist + (size_t)s * E;
        // layer 0: A=Qcomb x h1(s-1), B=Qhh0 x h0(s-1)
        k_stepq<<<E / 4, 256, 0, stream>>>(PA0, sA0, PB0, sB0, h1p, h0p, bcomb, c0, h0n);
        // layer 1: A=Qih1 x h0(s), B=Qhh1 x h1(s-1)
        k_stepq<<<E / 4, 256, 0, stream>>>(PA1, sA1, PB1, sB1, h0n, h1p, bias1, c1, h1n);
    }

    k_out<<<T_STEPS, 128, 0, stream>>>(woutT, hist, bout, (float*)d_out);
}